// Round 1
// baseline (1111.726 us; speedup 1.0000x reference)
//
#include <hip/hip_runtime.h>
#include <cmath>

#define NLEV 16
#define TPB 256

typedef float v4f __attribute__((ext_vector_type(4)));
typedef float v2f __attribute__((ext_vector_type(2)));

// Level metadata replicated from the reference's _level_meta() (float64 host
// math; boundary levels 5/10/15 land 1e-5 ABOVE the integer -> res=65/257/1025).
static constexpr unsigned kRes[NLEV] = {16u,22u,28u,37u,49u,65u,85u,112u,148u,195u,257u,338u,446u,589u,777u,1025u};
static constexpr unsigned kMsz[NLEV] = {4096u,10648u,21952u,50656u,117656u,274632u,
  524288u,524288u,524288u,524288u,524288u,524288u,524288u,524288u,524288u,524288u};
static constexpr unsigned kOff[NLEV] = {0u,4096u,14744u,36696u,87352u,205008u,479640u,1003928u,
  1528216u,2052504u,2576792u,3101080u,3625368u,4149656u,4673944u,5198232u};
static constexpr int kDense[NLEV] = {1,1,1,1,1,1,0,0,0,0,0,0,0,0,0,0};

struct ScaleParams { float s[NLEV]; };

// 16-B load that is only guaranteed 8-B aligned (dense corner-pair load).
// gfx950 global loads support dword alignment; worst case the backend splits
// into 2x dwordx2 which equals the old two-float2 path.
__device__ __forceinline__ v4f load4_a8(const float* p) {
  const float* q = (const float*)__builtin_assume_aligned((const void*)p, 8);
  v4f v;
  __builtin_memcpy(&v, q, 16);
  return v;
}

// Stage 512 points (2 per thread) of positions through LDS.
__device__ __forceinline__ void load_pos2(const float* __restrict__ pos, float* sp,
                                          int tid, size_t pbase,
                                          float& px0, float& py0, float& pz0,
                                          float& px1, float& py1, float& pz1) {
  const float* src = pos + pbase * 3;
#pragma unroll
  for (int k = 0; k < 6; ++k)
    sp[tid + k * TPB] = __builtin_nontemporal_load(src + tid + k * TPB);
  __syncthreads();
  px0 = sp[tid * 6 + 0]; py0 = sp[tid * 6 + 1]; pz0 = sp[tid * 6 + 2];
  px1 = sp[tid * 6 + 3]; py1 = sp[tid * 6 + 4]; pz1 = sp[tid * 6 + 5];
}

// One point, one dense level: 4 paired-corner 16-B gathers (x and x+1 corners
// are adjacent entries). Accumulation order matches the original 8-corner loop
// exactly (corner 2c then 2c+1, weights computed as (wx*wy)*wz).
__device__ __forceinline__ v2f dense_point(const float2* __restrict__ tab2,
                                           float px, float py, float pz,
                                           float scale, unsigned r, unsigned msz,
                                           unsigned off) {
  const float x = px * scale + 0.5f;
  const float y = py * scale + 0.5f;
  const float z = pz * scale + 0.5f;
  const float xf = floorf(x), yf = floorf(y), zf = floorf(z);
  const float tx = x - xf, ty = y - yf, tz = z - zf;
  const unsigned xi = (unsigned)xf, yi = (unsigned)yf, zi = (unsigned)zf;

  const unsigned hy[2] = {yi * r, (yi + 1u) * r};
  const unsigned hz[2] = {zi * r * r, (zi + 1u) * r * r};
  const float wx0 = 1.0f - tx, wx1 = tx;
  const float wy[2] = {1.0f - ty, ty};
  const float wz[2] = {1.0f - tz, tz};

  // wrap-patch value: corner x+1 of cell with idx==msz-1 lives at entry 0.
  // Uniform address -> scalar load, hoisted once per level.
  const float2 g = tab2[off];

  float a0 = 0.0f, a1 = 0.0f;
#pragma unroll
  for (int c = 0; c < 4; ++c) {
    // base corner (x=xi): h <= (r-1) + r*r + r*r^2 < 2*msz, so one cond-subtract.
    const unsigned h = xi + hy[c & 1] + hz[c >> 1];
    const unsigned idx = (h >= msz) ? (h - msz) : h;
    v4f f = load4_a8((const float*)(tab2 + (off + idx)));
    const bool wrap = (idx == msz - 1u);   // x+1 corner wraps to entry 0
    f.z = wrap ? g.x : f.z;
    f.w = wrap ? g.y : f.w;
    const float wyv = wy[c & 1], wzv = wz[c >> 1];
    const float w0 = (wx0 * wyv) * wzv;
    const float w1 = (wx1 * wyv) * wzv;
    a0 = fmaf(w0, f.x, a0);
    a1 = fmaf(w0, f.y, a1);
    a0 = fmaf(w1, f.z, a0);
    a1 = fmaf(w1, f.w, a1);
  }
  v2f rr; rr.x = a0; rr.y = a1;
  return rr;
}

// One point, one hashed level (msz == 524288 for all hashed levels).
__device__ __forceinline__ v2f hash_point(const float2* __restrict__ tab2,
                                          float px, float py, float pz,
                                          float scale, unsigned off) {
  const float x = px * scale + 0.5f;
  const float y = py * scale + 0.5f;
  const float z = pz * scale + 0.5f;
  const float xf = floorf(x), yf = floorf(y), zf = floorf(z);
  const float tx = x - xf, ty = y - yf, tz = z - zf;
  const unsigned xi = (unsigned)xf, yi = (unsigned)yf, zi = (unsigned)zf;

  const unsigned hx[2] = {xi, xi + 1u};
  const unsigned hy[2] = {yi * 2654435761u, (yi + 1u) * 2654435761u};
  const unsigned hz[2] = {zi * 805459861u,  (zi + 1u) * 805459861u};
  const float wx[2] = {1.0f - tx, tx};
  const float wy[2] = {1.0f - ty, ty};
  const float wz[2] = {1.0f - tz, tz};

  float a0 = 0.0f, a1 = 0.0f;
#pragma unroll
  for (int c = 0; c < 8; ++c) {
    const unsigned idx = (hx[c & 1] ^ hy[(c >> 1) & 1] ^ hz[(c >> 2) & 1]) & 524287u;
    const float2 f = tab2[off + idx];
    const float w = wx[c & 1] * wy[(c >> 1) & 1] * wz[(c >> 2) & 1];
    a0 = fmaf(w, f.x, a0);
    a1 = fmaf(w, f.y, a1);
  }
  v2f rr; rr.x = a0; rr.y = a1;
  return rr;
}

// ---------------------------------------------------------------------------
// Staged path, round 1 of polish: 2 points/thread, dense paired-corner loads,
// all 10 hashed levels fused into ONE dispatch (level-major block mapping
// keeps each level's 4MB table L2-resident; window of resident blocks is far
// smaller than the 4096 blocks per level).
// ---------------------------------------------------------------------------

__global__ __launch_bounds__(TPB, 4) void dense_levels2(
    const float* __restrict__ pos, const float* __restrict__ table,
    float* __restrict__ ws, ScaleParams spar, int npts)
{
  __shared__ float sp[TPB * 6];
  const int tid = threadIdx.x;
  const size_t pbase = (size_t)blockIdx.x * (TPB * 2);
  float px0, py0, pz0, px1, py1, pz1;
  load_pos2(pos, sp, tid, pbase, px0, py0, pz0, px1, py1, pz1);

  const float2* __restrict__ tab2 = (const float2*)table;
#pragma unroll
  for (int L = 0; L < 6; ++L) {
    const v2f r0 = dense_point(tab2, px0, py0, pz0, spar.s[L], kRes[L], kMsz[L], kOff[L]);
    const v2f r1 = dense_point(tab2, px1, py1, pz1, spar.s[L], kRes[L], kMsz[L], kOff[L]);
    v4f v; v.x = r0.x; v.y = r0.y; v.z = r1.x; v.w = r1.y;
    __builtin_nontemporal_store(v, (v4f*)ws + ((size_t)L * npts + pbase) / 2 + tid);
  }
}

__global__ __launch_bounds__(TPB, 4) void hash_fused(
    const float* __restrict__ pos, const float* __restrict__ table,
    float* __restrict__ ws, ScaleParams spar, int lvlShift, int npts)
{
  __shared__ float sp[TPB * 6];
  const int tid = threadIdx.x;
  const int lvl = 6 + (int)(blockIdx.x >> lvlShift);
  const unsigned pb = blockIdx.x & ((1u << lvlShift) - 1u);

  // uniform scalar select of this block's scale (avoids dynamic kernarg index)
  float scale = 0.0f;
#pragma unroll
  for (int l = 6; l < NLEV; ++l) if (l == lvl) scale = spar.s[l];
  const unsigned off = kOff[6] + (unsigned)(lvl - 6) * 524288u;

  const size_t pbase = (size_t)pb * (TPB * 2);
  float px0, py0, pz0, px1, py1, pz1;
  load_pos2(pos, sp, tid, pbase, px0, py0, pz0, px1, py1, pz1);

  const float2* __restrict__ tab2 = (const float2*)table;
  const v2f r0 = hash_point(tab2, px0, py0, pz0, scale, off);
  const v2f r1 = hash_point(tab2, px1, py1, pz1, scale, off);
  v4f v; v.x = r0.x; v.y = r0.y; v.z = r1.x; v.w = r1.y;
  __builtin_nontemporal_store(v, (v4f*)ws + ((size_t)lvl * npts + pbase) / 2 + tid);
}

__global__ __launch_bounds__(TPB, 4) void transpose_out(
    const float* __restrict__ ws, float* __restrict__ out, int npts)
{
  __shared__ float lds[TPB * 33];
  const int tid = threadIdx.x;
  const size_t pbase = (size_t)blockIdx.x * TPB;
#pragma unroll
  for (int L = 0; L < NLEV; ++L) {
    const v2f w = __builtin_nontemporal_load((const v2f*)ws + (size_t)L * npts + pbase + tid);
    lds[tid * 33 + 2 * L]     = w.x;
    lds[tid * 33 + 2 * L + 1] = w.y;
  }
  __syncthreads();
  v4f* out4 = (v4f*)out + (size_t)blockIdx.x * (TPB * 32 / 4);
#pragma unroll
  for (int k = 0; k < 8; ++k) {
    const int q  = tid + k * TPB;
    const int p  = q >> 3;
    const int c4 = (q & 7) * 4;
    v4f v;
    v.x = lds[p * 33 + c4 + 0];
    v.y = lds[p * 33 + c4 + 1];
    v.z = lds[p * 33 + c4 + 2];
    v.w = lds[p * 33 + c4 + 3];
    __builtin_nontemporal_store(v, out4 + q);
  }
}

// ---------------------------------------------------------------------------
// Fallback monolithic kernel (R2: passed, 1300us) if ws is too small or the
// grid geometry assumptions don't hold.
// ---------------------------------------------------------------------------
__global__ __launch_bounds__(TPB) void hashenc_kernel(
    const float* __restrict__ pos, const float* __restrict__ table,
    float* __restrict__ out, ScaleParams spar)
{
  __shared__ float lds[TPB * 33];
  const int tid = threadIdx.x;
  const size_t pbase = (size_t)blockIdx.x * TPB;
  {
    const float* src = pos + pbase * 3;
    lds[tid]        = src[tid];
    lds[tid + 256]  = src[tid + 256];
    lds[tid + 512]  = src[tid + 512];
  }
  __syncthreads();
  const float px = lds[tid*3 + 0];
  const float py = lds[tid*3 + 1];
  const float pz = lds[tid*3 + 2];
  __syncthreads();

  const float2* __restrict__ tab2 = (const float2*)table;
  float acc[2 * NLEV];

#pragma unroll
  for (int L = 0; L < NLEV; ++L) {
    const float scale = spar.s[L];
    const float x = px * scale + 0.5f;
    const float y = py * scale + 0.5f;
    const float z = pz * scale + 0.5f;
    const float xf = floorf(x), yf = floorf(y), zf = floorf(z);
    const float tx = x - xf, ty = y - yf, tz = z - zf;
    const unsigned xi = (unsigned)xf, yi = (unsigned)yf, zi = (unsigned)zf;

    unsigned hx[2], hy[2], hz[2];
    if (kDense[L]) {
      const unsigned r = kRes[L];
      hx[0] = xi;          hx[1] = xi + 1u;
      hy[0] = yi * r;      hy[1] = (yi + 1u) * r;
      hz[0] = zi * r * r;  hz[1] = (zi + 1u) * r * r;
    } else {
      hx[0] = xi;                 hx[1] = xi + 1u;
      hy[0] = yi * 2654435761u;   hy[1] = (yi + 1u) * 2654435761u;
      hz[0] = zi * 805459861u;    hz[1] = (zi + 1u) * 805459861u;
    }
    const float wx[2] = {1.0f - tx, tx};
    const float wy[2] = {1.0f - ty, ty};
    const float wz[2] = {1.0f - tz, tz};

    float a0 = 0.0f, a1 = 0.0f;
#pragma unroll
    for (int c = 0; c < 8; ++c) {
      unsigned idx;
      if (kDense[L]) {
        unsigned h = hx[c & 1] + hy[(c >> 1) & 1] + hz[(c >> 2) & 1];
        idx = (h >= kMsz[L]) ? (h - kMsz[L]) : h;
      } else {
        idx = (hx[c & 1] ^ hy[(c >> 1) & 1] ^ hz[(c >> 2) & 1]) & (kMsz[L] - 1u);
      }
      const float2 f = tab2[kOff[L] + idx];
      const float w = wx[c & 1] * wy[(c >> 1) & 1] * wz[(c >> 2) & 1];
      a0 = fmaf(w, f.x, a0);
      a1 = fmaf(w, f.y, a1);
    }
    acc[2 * L]     = a0;
    acc[2 * L + 1] = a1;
  }

#pragma unroll
  for (int c = 0; c < 32; ++c) lds[tid * 33 + c] = acc[c];
  __syncthreads();

  v4f* out4 = (v4f*)out + (size_t)blockIdx.x * (TPB * 32 / 4);
#pragma unroll
  for (int k = 0; k < 8; ++k) {
    const int q  = tid + k * TPB;
    const int p  = q >> 3;
    const int c4 = (q & 7) * 4;
    v4f v;
    v.x = lds[p * 33 + c4 + 0];
    v.y = lds[p * 33 + c4 + 1];
    v.z = lds[p * 33 + c4 + 2];
    v.w = lds[p * 33 + c4 + 3];
    __builtin_nontemporal_store(v, out4 + q);
  }
}

extern "C" void kernel_launch(void* const* d_in, const int* in_sizes, int n_in,
                              void* d_out, int out_size, void* d_ws, size_t ws_size,
                              hipStream_t stream) {
  const float* pos   = (const float*)d_in[0];
  const float* table = (const float*)d_in[1];
  float* out = (float*)d_out;

  ScaleParams sp;
  for (int i = 0; i < NLEV; ++i)
    sp.s[i] = (float)(16.0 * exp((double)i * log(1.3195079565048218)) - 1.0);

  const int npts = in_sizes[0] / 3;   // 2097152
  const size_t need = (size_t)npts * 32 * sizeof(float);

  const int npair = npts / (TPB * 2);            // blocks per level at 2 pts/thread
  int sh = 0; while ((1 << sh) < npair) ++sh;
  const bool ok = (npts % (TPB * 2) == 0) && ((1 << sh) == npair);

  if (ws_size >= need && ok) {
    float* wsf = (float*)d_ws;
    dense_levels2<<<npair, TPB, 0, stream>>>(pos, table, wsf, sp, npts);
    hash_fused<<<npair * 10, TPB, 0, stream>>>(pos, table, wsf, sp, sh, npts);
    transpose_out<<<npts / TPB, TPB, 0, stream>>>(wsf, out, npts);
  } else {
    hashenc_kernel<<<npts / TPB, TPB, 0, stream>>>(pos, table, out, sp);
  }
}

// Round 2
// 1007.688 us; speedup vs baseline: 1.1032x; 1.1032x over previous
//
#include <hip/hip_runtime.h>
#include <cmath>

#define NLEV 16
#define TPB 256

typedef float v4f __attribute__((ext_vector_type(4)));
typedef float v2f __attribute__((ext_vector_type(2)));

// Level metadata replicated from the reference's _level_meta() (float64 host
// math; boundary levels 5/10/15 land 1e-5 ABOVE the integer -> res=65/257/1025).
static constexpr unsigned kRes[NLEV] = {16u,22u,28u,37u,49u,65u,85u,112u,148u,195u,257u,338u,446u,589u,777u,1025u};
static constexpr unsigned kMsz[NLEV] = {4096u,10648u,21952u,50656u,117656u,274632u,
  524288u,524288u,524288u,524288u,524288u,524288u,524288u,524288u,524288u,524288u};
static constexpr unsigned kOff[NLEV] = {0u,4096u,14744u,36696u,87352u,205008u,479640u,1003928u,
  1528216u,2052504u,2576792u,3101080u,3625368u,4149656u,4673944u,5198232u};
static constexpr int kDense[NLEV] = {1,1,1,1,1,1,0,0,0,0,0,0,0,0,0,0};

struct ScaleParams { float s[NLEV]; };

// Stage 512 points (2 per thread) of positions through LDS.
__device__ __forceinline__ void load_pos2(const float* __restrict__ pos, float* sp,
                                          int tid, size_t pbase,
                                          float& px0, float& py0, float& pz0,
                                          float& px1, float& py1, float& pz1) {
  const float* src = pos + pbase * 3;
#pragma unroll
  for (int k = 0; k < 6; ++k)
    sp[tid + k * TPB] = __builtin_nontemporal_load(src + tid + k * TPB);
  __syncthreads();
  px0 = sp[tid * 6 + 0]; py0 = sp[tid * 6 + 1]; pz0 = sp[tid * 6 + 2];
  px1 = sp[tid * 6 + 3]; py1 = sp[tid * 6 + 4]; pz1 = sp[tid * 6 + 5];
}

// Per-point index+weight setup, dense (indicator==1) addressing.
// Identical arithmetic/order to the verified round-0 kernel.
__device__ __forceinline__ void dense_setup(float px, float py, float pz,
                                            float scale, unsigned r, unsigned msz,
                                            unsigned* idx, float* w) {
  const float x = px * scale + 0.5f;
  const float y = py * scale + 0.5f;
  const float z = pz * scale + 0.5f;
  const float xf = floorf(x), yf = floorf(y), zf = floorf(z);
  const float tx = x - xf, ty = y - yf, tz = z - zf;
  const unsigned xi = (unsigned)xf, yi = (unsigned)yf, zi = (unsigned)zf;

  const unsigned hx[2] = {xi, xi + 1u};
  const unsigned hy[2] = {yi * r, (yi + 1u) * r};
  const unsigned hz[2] = {zi * r * r, (zi + 1u) * r * r};
  const float wx[2] = {1.0f - tx, tx};
  const float wy[2] = {1.0f - ty, ty};
  const float wz[2] = {1.0f - tz, tz};

#pragma unroll
  for (int c = 0; c < 8; ++c) {
    // h < 2*msz provably (h <= r*(1+r+r^2) < 2*r^3 <= 2*msz)
    const unsigned h = hx[c & 1] + hy[(c >> 1) & 1] + hz[(c >> 2) & 1];
    idx[c] = (h >= msz) ? (h - msz) : h;
    w[c]   = wx[c & 1] * wy[(c >> 1) & 1] * wz[(c >> 2) & 1];
  }
}

// Per-point index+weight setup, hashed addressing (msz == 524288 everywhere).
__device__ __forceinline__ void hash_setup(float px, float py, float pz, float scale,
                                           unsigned* idx, float* w) {
  const float x = px * scale + 0.5f;
  const float y = py * scale + 0.5f;
  const float z = pz * scale + 0.5f;
  const float xf = floorf(x), yf = floorf(y), zf = floorf(z);
  const float tx = x - xf, ty = y - yf, tz = z - zf;
  const unsigned xi = (unsigned)xf, yi = (unsigned)yf, zi = (unsigned)zf;

  const unsigned hx[2] = {xi, xi + 1u};
  const unsigned hy[2] = {yi * 2654435761u, (yi + 1u) * 2654435761u};
  const unsigned hz[2] = {zi * 805459861u,  (zi + 1u) * 805459861u};
  const float wx[2] = {1.0f - tx, tx};
  const float wy[2] = {1.0f - ty, ty};
  const float wz[2] = {1.0f - tz, tz};

#pragma unroll
  for (int c = 0; c < 8; ++c) {
    idx[c] = (hx[c & 1] ^ hy[(c >> 1) & 1] ^ hz[(c >> 2) & 1]) & 524287u;
    w[c]   = wx[c & 1] * wy[(c >> 1) & 1] * wz[(c >> 2) & 1];
  }
}

// ---------------------------------------------------------------------------
// Staged path, round 2 of polish.
// Key change: batch-issue ALL 16 gathers (2 points x 8 corners) into registers
// before any FMA, pinned with sched_barrier(0). Round-1 counters showed
// VGPR_Count=32 -> compiler sank loads next to uses -> only ~5 gathers in
// flight per wave -> latency-bound at 2.2 cyc/request. Trading VGPR/occupancy
// for 16 outstanding gathers per wave saturates the TA/L2 path instead.
// ---------------------------------------------------------------------------

__global__ __launch_bounds__(TPB, 4) void dense_levels2(
    const float* __restrict__ pos, const float* __restrict__ table,
    float* __restrict__ ws, ScaleParams spar, int npts)
{
  __shared__ float sp[TPB * 6];
  const int tid = threadIdx.x;
  const size_t pbase = (size_t)blockIdx.x * (TPB * 2);
  float px0, py0, pz0, px1, py1, pz1;
  load_pos2(pos, sp, tid, pbase, px0, py0, pz0, px1, py1, pz1);

#pragma unroll
  for (int L = 0; L < 6; ++L) {
    unsigned i0[8], i1[8];
    float    w0[8], w1[8];
    dense_setup(px0, py0, pz0, spar.s[L], kRes[L], kMsz[L], i0, w0);
    dense_setup(px1, py1, pz1, spar.s[L], kRes[L], kMsz[L], i1, w1);

    const v2f* __restrict__ t2 = (const v2f*)table + kOff[L];
    v2f f0[8], f1[8];
#pragma unroll
    for (int c = 0; c < 8; ++c) f0[c] = t2[i0[c]];
#pragma unroll
    for (int c = 0; c < 8; ++c) f1[c] = t2[i1[c]];
    __builtin_amdgcn_sched_barrier(0);   // keep all 16 gathers issued before use

    float a0 = 0.0f, a1 = 0.0f, b0 = 0.0f, b1 = 0.0f;
#pragma unroll
    for (int c = 0; c < 8; ++c) { a0 = fmaf(w0[c], f0[c].x, a0); a1 = fmaf(w0[c], f0[c].y, a1); }
#pragma unroll
    for (int c = 0; c < 8; ++c) { b0 = fmaf(w1[c], f1[c].x, b0); b1 = fmaf(w1[c], f1[c].y, b1); }

    v4f v; v.x = a0; v.y = a1; v.z = b0; v.w = b1;
    __builtin_nontemporal_store(v, (v4f*)ws + ((size_t)L * npts + pbase) / 2 + tid);
  }
}

__global__ __launch_bounds__(TPB, 4) void hash_fused(
    const float* __restrict__ pos, const float* __restrict__ table,
    float* __restrict__ ws, ScaleParams spar, int lvlShift, int npts)
{
  __shared__ float sp[TPB * 6];
  const int tid = threadIdx.x;
  const int lvl = 6 + (int)(blockIdx.x >> lvlShift);
  const unsigned pb = blockIdx.x & ((1u << lvlShift) - 1u);

  // uniform scalar select of this block's scale (avoids dynamic kernarg index)
  float scale = 0.0f;
#pragma unroll
  for (int l = 6; l < NLEV; ++l) if (l == lvl) scale = spar.s[l];
  const unsigned off = kOff[6] + (unsigned)(lvl - 6) * 524288u;

  const size_t pbase = (size_t)pb * (TPB * 2);
  float px0, py0, pz0, px1, py1, pz1;
  load_pos2(pos, sp, tid, pbase, px0, py0, pz0, px1, py1, pz1);

  unsigned i0[8], i1[8];
  float    w0[8], w1[8];
  hash_setup(px0, py0, pz0, scale, i0, w0);
  hash_setup(px1, py1, pz1, scale, i1, w1);

  const v2f* __restrict__ t2 = (const v2f*)table + off;
  v2f f0[8], f1[8];
#pragma unroll
  for (int c = 0; c < 8; ++c) f0[c] = t2[i0[c]];
#pragma unroll
  for (int c = 0; c < 8; ++c) f1[c] = t2[i1[c]];
  __builtin_amdgcn_sched_barrier(0);     // keep all 16 gathers issued before use

  float a0 = 0.0f, a1 = 0.0f, b0 = 0.0f, b1 = 0.0f;
#pragma unroll
  for (int c = 0; c < 8; ++c) { a0 = fmaf(w0[c], f0[c].x, a0); a1 = fmaf(w0[c], f0[c].y, a1); }
#pragma unroll
  for (int c = 0; c < 8; ++c) { b0 = fmaf(w1[c], f1[c].x, b0); b1 = fmaf(w1[c], f1[c].y, b1); }

  v4f v; v.x = a0; v.y = a1; v.z = b0; v.w = b1;
  __builtin_nontemporal_store(v, (v4f*)ws + ((size_t)lvl * npts + pbase) / 2 + tid);
}

__global__ __launch_bounds__(TPB, 4) void transpose_out(
    const float* __restrict__ ws, float* __restrict__ out, int npts)
{
  __shared__ float lds[TPB * 33];
  const int tid = threadIdx.x;
  const size_t pbase = (size_t)blockIdx.x * TPB;
#pragma unroll
  for (int L = 0; L < NLEV; ++L) {
    const v2f w = __builtin_nontemporal_load((const v2f*)ws + (size_t)L * npts + pbase + tid);
    lds[tid * 33 + 2 * L]     = w.x;
    lds[tid * 33 + 2 * L + 1] = w.y;
  }
  __syncthreads();
  v4f* out4 = (v4f*)out + (size_t)blockIdx.x * (TPB * 32 / 4);
#pragma unroll
  for (int k = 0; k < 8; ++k) {
    const int q  = tid + k * TPB;
    const int p  = q >> 3;
    const int c4 = (q & 7) * 4;
    v4f v;
    v.x = lds[p * 33 + c4 + 0];
    v.y = lds[p * 33 + c4 + 1];
    v.z = lds[p * 33 + c4 + 2];
    v.w = lds[p * 33 + c4 + 3];
    __builtin_nontemporal_store(v, out4 + q);
  }
}

// ---------------------------------------------------------------------------
// Fallback monolithic kernel (proven correct) if ws is too small or the grid
// geometry assumptions don't hold.
// ---------------------------------------------------------------------------
__global__ __launch_bounds__(TPB) void hashenc_kernel(
    const float* __restrict__ pos, const float* __restrict__ table,
    float* __restrict__ out, ScaleParams spar)
{
  __shared__ float lds[TPB * 33];
  const int tid = threadIdx.x;
  const size_t pbase = (size_t)blockIdx.x * TPB;
  {
    const float* src = pos + pbase * 3;
    lds[tid]        = src[tid];
    lds[tid + 256]  = src[tid + 256];
    lds[tid + 512]  = src[tid + 512];
  }
  __syncthreads();
  const float px = lds[tid*3 + 0];
  const float py = lds[tid*3 + 1];
  const float pz = lds[tid*3 + 2];
  __syncthreads();

  const float2* __restrict__ tab2 = (const float2*)table;
  float acc[2 * NLEV];

#pragma unroll
  for (int L = 0; L < NLEV; ++L) {
    const float scale = spar.s[L];
    const float x = px * scale + 0.5f;
    const float y = py * scale + 0.5f;
    const float z = pz * scale + 0.5f;
    const float xf = floorf(x), yf = floorf(y), zf = floorf(z);
    const float tx = x - xf, ty = y - yf, tz = z - zf;
    const unsigned xi = (unsigned)xf, yi = (unsigned)yf, zi = (unsigned)zf;

    unsigned hx[2], hy[2], hz[2];
    if (kDense[L]) {
      const unsigned r = kRes[L];
      hx[0] = xi;          hx[1] = xi + 1u;
      hy[0] = yi * r;      hy[1] = (yi + 1u) * r;
      hz[0] = zi * r * r;  hz[1] = (zi + 1u) * r * r;
    } else {
      hx[0] = xi;                 hx[1] = xi + 1u;
      hy[0] = yi * 2654435761u;   hy[1] = (yi + 1u) * 2654435761u;
      hz[0] = zi * 805459861u;    hz[1] = (zi + 1u) * 805459861u;
    }
    const float wx[2] = {1.0f - tx, tx};
    const float wy[2] = {1.0f - ty, ty};
    const float wz[2] = {1.0f - tz, tz};

    float a0 = 0.0f, a1 = 0.0f;
#pragma unroll
    for (int c = 0; c < 8; ++c) {
      unsigned idx;
      if (kDense[L]) {
        unsigned h = hx[c & 1] + hy[(c >> 1) & 1] + hz[(c >> 2) & 1];
        idx = (h >= kMsz[L]) ? (h - kMsz[L]) : h;
      } else {
        idx = (hx[c & 1] ^ hy[(c >> 1) & 1] ^ hz[(c >> 2) & 1]) & (kMsz[L] - 1u);
      }
      const float2 f = tab2[kOff[L] + idx];
      const float w = wx[c & 1] * wy[(c >> 1) & 1] * wz[(c >> 2) & 1];
      a0 = fmaf(w, f.x, a0);
      a1 = fmaf(w, f.y, a1);
    }
    acc[2 * L]     = a0;
    acc[2 * L + 1] = a1;
  }

#pragma unroll
  for (int c = 0; c < 32; ++c) lds[tid * 33 + c] = acc[c];
  __syncthreads();

  v4f* out4 = (v4f*)out + (size_t)blockIdx.x * (TPB * 32 / 4);
#pragma unroll
  for (int k = 0; k < 8; ++k) {
    const int q  = tid + k * TPB;
    const int p  = q >> 3;
    const int c4 = (q & 7) * 4;
    v4f v;
    v.x = lds[p * 33 + c4 + 0];
    v.y = lds[p * 33 + c4 + 1];
    v.z = lds[p * 33 + c4 + 2];
    v.w = lds[p * 33 + c4 + 3];
    __builtin_nontemporal_store(v, out4 + q);
  }
}

extern "C" void kernel_launch(void* const* d_in, const int* in_sizes, int n_in,
                              void* d_out, int out_size, void* d_ws, size_t ws_size,
                              hipStream_t stream) {
  const float* pos   = (const float*)d_in[0];
  const float* table = (const float*)d_in[1];
  float* out = (float*)d_out;

  ScaleParams sp;
  for (int i = 0; i < NLEV; ++i)
    sp.s[i] = (float)(16.0 * exp((double)i * log(1.3195079565048218)) - 1.0);

  const int npts = in_sizes[0] / 3;   // 2097152
  const size_t need = (size_t)npts * 32 * sizeof(float);

  const int npair = npts / (TPB * 2);            // blocks per level at 2 pts/thread
  int sh = 0; while ((1 << sh) < npair) ++sh;
  const bool ok = (npts % (TPB * 2) == 0) && ((1 << sh) == npair);

  if (ws_size >= need && ok) {
    float* wsf = (float*)d_ws;
    dense_levels2<<<npair, TPB, 0, stream>>>(pos, table, wsf, sp, npts);
    hash_fused<<<npair * 10, TPB, 0, stream>>>(pos, table, wsf, sp, sh, npts);
    transpose_out<<<npts / TPB, TPB, 0, stream>>>(wsf, out, npts);
  } else {
    hashenc_kernel<<<npts / TPB, TPB, 0, stream>>>(pos, table, out, sp);
  }
}